// Round 5
// baseline (11595.963 us; speedup 1.0000x reference)
//
#include <hip/hip_runtime.h>
#include <cstdint>

#define NB 4
#define NN 4096
#define LL 256
#define KTOP 20
#define EPSF 1e-6f
#define CSPLIT 8
#define NCAND (CSPLIT * KTOP)   // 160
#define KD 512          // storage: [hi(256) | lo(256)] fp16 per row

typedef _Float16 f16x8 __attribute__((ext_vector_type(8)));
typedef _Float16 f16x4 __attribute__((ext_vector_type(4)));
typedef float f32x16 __attribute__((ext_vector_type(16)));

// ---------------- Kernel 0: per-row stats + fp16 hi/lo split ----------------
__global__ __launch_bounds__(64) void stats_split(const float* __restrict__ hist,
                                                  _Float16* __restrict__ xd) {
    int row = blockIdx.x;              // 0 .. B*N-1
    int lane = threadIdx.x;            // 0 .. 63
    float4 v = reinterpret_cast<const float4*>(hist + (size_t)row * LL)[lane];
    float s = v.x + v.y + v.z + v.w;
    #pragma unroll
    for (int off = 32; off; off >>= 1) s += __shfl_xor(s, off);
    float mean = s * (1.0f / 256.0f);
    float c0 = v.x - mean, c1 = v.y - mean, c2 = v.z - mean, c3 = v.w - mean;
    float ss = c0*c0 + c1*c1 + c2*c2 + c3*c3;
    #pragma unroll
    for (int off = 32; off; off >>= 1) ss += __shfl_xor(ss, off);
    float inv = 1.0f / fmaxf(sqrtf(ss * (1.0f / 256.0f)), EPSF);
    float n0 = c0*inv, n1 = c1*inv, n2 = c2*inv, n3 = c3*inv;
    f16x4 h, lo;
    h[0] = (_Float16)n0; h[1] = (_Float16)n1; h[2] = (_Float16)n2; h[3] = (_Float16)n3;
    lo[0] = (_Float16)(n0 - (float)h[0]);
    lo[1] = (_Float16)(n1 - (float)h[1]);
    lo[2] = (_Float16)(n2 - (float)h[2]);
    lo[3] = (_Float16)(n3 - (float)h[3]);
    _Float16* base = xd + (size_t)row * KD + lane * 4;
    *(f16x4*)base = h;
    *(f16x4*)(base + 256) = lo;
}

// ------- Kernel 1: fp16 split-product MFMA GEMM + register-resident top-20 -------
// dot = hi.hi' + hi.lo' + lo.hi'  (lo.lo' ~ 2^-22, dropped)  => fp32-parity sim.
// block: 256 thr (4 waves). 128 rows/block, 512 cols (CSPLIT=8), col-tiles of 128.
// 64-k LDS chunks -> As+Bs = 32 KB -> 4 blocks/CU resident (grid 1024 = 4/CU).
#define INSERT(MM, OFF, LVR, LIR)                                       \
    while (MM) {                                                        \
        int cbit = __ffs(MM) - 1; MM &= MM - 1;                         \
        float val = __shfl(vv, cbit + OFF);                             \
        float mn = __shfl(LVR, 19);                                     \
        if (val > mn) {                                                 \
            unsigned long long ge = __ballot(LVR >= val);               \
            int pos = __popcll(ge & 0xFFFFFull);                        \
            float sv = __shfl_up(LVR, 1);                               \
            int si = __shfl_up(LIR, 1);                                 \
            int colv = colbase + cbit;                                  \
            LVR = (l < pos) ? LVR : ((l == pos) ? val : sv);            \
            LIR = (l < pos) ? LIR : ((l == pos) ? colv : si);           \
        }                                                               \
    }

__global__ __launch_bounds__(256, 4) void gemm_topk(const _Float16* __restrict__ xd,
                                                    float* __restrict__ listv,
                                                    short* __restrict__ listi) {
    __shared__ __align__(16) char As[16384];   // 128 rows x 64 k x 2B
    __shared__ __align__(16) char Bs[16384];   // 128 cols x 64 k x 2B

    const int tid = threadIdx.x;
    const int w = tid >> 6;
    const int l = tid & 63;

    const int bid = blockIdx.x;                // ((b*32 + rowblk)*8 + cs)
    const int cs = bid & 7;
    const int rowblk = (bid >> 3) & 31;
    const int b = bid >> 8;
    const int r0 = rowblk * 128;
    const size_t nbase = (size_t)b * NN;
    const _Float16* xb = xd + nbase * KD;

    float lv[32]; int li[32];
    #pragma unroll
    for (int r = 0; r < 32; ++r) { lv[r] = -1.0f; li[r] = -1; }

    // staging lane constants: one 1KB instr = 8 rows x 128 B; lane l -> row l>>3, slot l&7
    const int srow = l >> 3;
    const int sslot = l & 7;
    const int skl = (sslot ^ srow) * 8;        // pre-swizzled src k (f16 elems); row&7 == srow
    // fragment lane constants
    const int lrow = l & 31;
    const int kg2 = l >> 5;                    // k-half 0/1
    const int r7 = l & 7;                      // row&7 for both A (lrow) and B (j*32+lrow)
    const char* aRow = As + (w * 32 + lrow) * 128;
    const char* bRow = Bs + lrow * 128;

    f32x16 acc[4];

    for (int ct = 0; ct < 4; ++ct) {           // 4 col-tiles of 128
        const int c0 = cs * 512 + ct * 128;
        #pragma unroll
        for (int j = 0; j < 4; ++j)
            #pragma unroll
            for (int e = 0; e < 16; ++e) acc[j][e] = 0.0f;

        // 3-pass split product over 64-k chunks:
        // g=0: hi.hi' (aoff=q*64,     boff=q*64)
        // g=1: hi.lo' (aoff=q*64,     boff=256+q*64)
        // g=2: lo.hi' (aoff=256+q*64, boff=q*64)
        #pragma unroll
        for (int p = 0; p < 12; ++p) {
            const int g = p >> 2, q = p & 3;
            const int aoff = ((g < 2) ? 0 : 256) + q * 64;
            const int boff = ((g == 1) ? 256 : 0) + q * 64;
            __syncthreads();                   // prior readers of As/Bs done
            #pragma unroll
            for (int s = 0; s < 4; ++s) {
                const int i = w * 4 + s;       // 1KB instr index 0..15 (wave-uniform)
                const int row = i * 8 + srow;
                const _Float16* ga = xb + (size_t)(r0 + row) * KD + aoff + skl;
                __builtin_amdgcn_global_load_lds(
                    (const __attribute__((address_space(1))) void*)ga,
                    (__attribute__((address_space(3))) void*)(As + i * 1024), 16, 0, 0);
                const _Float16* gb = xb + (size_t)(c0 + row) * KD + boff + skl;
                __builtin_amdgcn_global_load_lds(
                    (const __attribute__((address_space(1))) void*)gb,
                    (__attribute__((address_space(3))) void*)(Bs + i * 1024), 16, 0, 0);
            }
            __syncthreads();                   // loads drained
            #pragma unroll
            for (int ks = 0; ks < 4; ++ks) {
                const int koff = ((ks * 2 + kg2) ^ r7) << 4;
                f16x8 a = *(const f16x8*)(aRow + koff);
                #pragma unroll
                for (int j = 0; j < 4; ++j) {
                    f16x8 bj = *(const f16x8*)(bRow + j * 4096 + koff);
                    acc[j] = __builtin_amdgcn_mfma_f32_32x32x16_f16(a, bj, acc[j], 0, 0, 0);
                }
            }
        }

        // ---- per-tile top-k scan (register lists, all-lane parallel insert) ----
        #pragma unroll
        for (int rg = 0; rg < 16; ++rg) {
            const int rA = (rg & 3) + 8 * (rg >> 2);      // compile-time
            const int rB = rA + 4;
            const int rowl = rA + ((l >> 5) << 2);
            const int grow = r0 + w * 32 + rowl;          // batch-local row
            float thrA = fmaxf(__shfl(lv[rA], 19), 0.0f);
            float thrB = fmaxf(__shfl(lv[rB], 19), 0.0f);
            float thr = (l < 32) ? thrA : thrB;
            #pragma unroll
            for (int j = 0; j < 4; ++j) {
                const int colbase = c0 + j * 32;
                float vv = fmaxf(acc[j][rg] * (1.0f / 256.0f), 0.0f);
                if (colbase + (l & 31) == grow) vv = 0.0f;  // zero diagonal
                unsigned long long m = __ballot(vv > thr);
                unsigned int mA = (unsigned int)m;
                unsigned int mB = (unsigned int)(m >> 32);
                INSERT(mA, 0, lv[rA], li[rA])
                INSERT(mB, 32, lv[rB], li[rB])
            }
        }
    }

    // write partial lists (20 per row per split)
    #pragma unroll
    for (int r = 0; r < 32; ++r) {
        size_t grow = nbase + r0 + w * 32 + r;
        size_t basep = (grow * CSPLIT + cs) * KTOP;
        if (l < KTOP) {
            listv[basep + l] = fmaxf(lv[r], 0.0f);   // dummies -> 0
            listi[basep + l] = (short)li[r];         // dummies -> -1 (never scattered)
        }
    }
}

// ------- Kernel 2: 8-way rank-merge + double row-normalize + write -------
__global__ __launch_bounds__(256) void merge_kernel(const float* __restrict__ listv,
                                                    const short* __restrict__ listi,
                                                    float* __restrict__ out) {
    __shared__ float ldsv[4][NCAND];
    __shared__ int   ldsi[4][NCAND];
    __shared__ float selv[4][KTOP];
    __shared__ int   seli[4][KTOP];
    const int tid = threadIdx.x;
    const int wv = tid >> 6;
    const int l = tid & 63;
    const size_t gr = (size_t)blockIdx.x * 4 + wv;    // global row 0..16383

    for (int q = l; q < NCAND; q += 64) {
        ldsv[wv][q] = listv[gr * NCAND + q];
        ldsi[wv][q] = (int)listi[gr * NCAND + q];
    }
    __syncthreads();

    // rank-select top-20 of 160: strict total order (val desc, idx asc, slot asc)
    const int q0 = l, q1 = l + 64, q2 = l + 128;
    float v0 = ldsv[wv][q0];                 int i0 = ldsi[wv][q0];
    float v1 = ldsv[wv][q1];                 int i1 = ldsi[wv][q1];
    float v2 = (l < 32) ? ldsv[wv][q2] : -2.0f;
    int   i2 = (l < 32) ? ldsi[wv][q2] : 0x7fffffff;
    int rank0 = 0, rank1 = 0, rank2 = 0;
    for (int p = 0; p < NCAND; ++p) {
        float vp = ldsv[wv][p]; int ip = ldsi[wv][p];
        rank0 += ((vp > v0) || (vp == v0 && (ip < i0 || (ip == i0 && p < q0)))) ? 1 : 0;
        rank1 += ((vp > v1) || (vp == v1 && (ip < i1 || (ip == i1 && p < q1)))) ? 1 : 0;
        rank2 += ((vp > v2) || (vp == v2 && (ip < i2 || (ip == i2 && p < q2)))) ? 1 : 0;
    }
    if (rank0 < KTOP) { selv[wv][rank0] = v0; seli[wv][rank0] = i0; }
    if (rank1 < KTOP) { selv[wv][rank1] = v1; seli[wv][rank1] = i1; }
    if (l < 32 && rank2 < KTOP) { selv[wv][rank2] = v2; seli[wv][rank2] = i2; }
    __syncthreads();

    // double row-normalize (matches reference: /max(sum,eps) twice)
    float wval = (l < KTOP) ? selv[wv][l] : 0.0f;
    int   widx = (l < KTOP) ? seli[wv][l] : -1;
    float s1 = wval;
    #pragma unroll
    for (int off = 32; off; off >>= 1) s1 += __shfl_xor(s1, off);
    float w1 = wval / fmaxf(s1, EPSF);
    float s2 = (l < KTOP) ? w1 : 0.0f;
    #pragma unroll
    for (int off = 32; off; off >>= 1) s2 += __shfl_xor(s2, off);
    float wf = w1 / fmaxf(s2, EPSF);

    // zero the 4 output rows (coalesced float4), then scatter 20 values per row
    float4* obase = reinterpret_cast<float4*>(out + (size_t)blockIdx.x * 4 * NN);
    float4 z = make_float4(0.f, 0.f, 0.f, 0.f);
    for (int i = tid; i < 4 * (NN / 4); i += 256) obase[i] = z;
    __syncthreads();
    if (l < KTOP && widx >= 0) out[gr * NN + widx] = wf;
}

extern "C" void kernel_launch(void* const* d_in, const int* in_sizes, int n_in,
                              void* d_out, int out_size, void* d_ws, size_t ws_size,
                              hipStream_t stream) {
    const float* hist = (const float*)d_in[0];
    // d_in[1] = mask [B,N] — all ones in this problem; ignored.
    char* ws = (char*)d_ws;
    const size_t xdBytes = (size_t)NB * NN * KD * sizeof(_Float16);        // 16.78 MB
    const size_t lvBytes = (size_t)NB * NN * NCAND * sizeof(float);        // 10.49 MB
    _Float16* xd = (_Float16*)ws;
    float* listv = (float*)(ws + xdBytes);
    short* listi = (short*)(ws + xdBytes + lvBytes);                        // 5.24 MB
    float* out = (float*)d_out;

    stats_split<<<NB * NN, 64, 0, stream>>>(hist, xd);
    gemm_topk<<<NB * 32 * CSPLIT, 256, 0, stream>>>(xd, listv, listi);
    merge_kernel<<<NB * NN / 4, 256, 0, stream>>>(listv, listi, out);
}

// Round 6
// 1066.384 us; speedup vs baseline: 10.8741x; 10.8741x over previous
//
#include <hip/hip_runtime.h>
#include <cstdint>

#define NB 4
#define NN 4096
#define LL 256
#define KTOP 20
#define EPSF 1e-6f
#define CSPLIT 8
#define NCAND (CSPLIT * KTOP)   // 160
#define KD 512          // storage: [hi(256) | lo(256)] fp16 per row

typedef _Float16 f16x8 __attribute__((ext_vector_type(8)));
typedef _Float16 f16x4 __attribute__((ext_vector_type(4)));
typedef float f32x16 __attribute__((ext_vector_type(16)));

// ---------------- Kernel 0: per-row stats + fp16 hi/lo split ----------------
__global__ __launch_bounds__(64) void stats_split(const float* __restrict__ hist,
                                                  _Float16* __restrict__ xd) {
    int row = blockIdx.x;              // 0 .. B*N-1
    int lane = threadIdx.x;            // 0 .. 63
    float4 v = reinterpret_cast<const float4*>(hist + (size_t)row * LL)[lane];
    float s = v.x + v.y + v.z + v.w;
    #pragma unroll
    for (int off = 32; off; off >>= 1) s += __shfl_xor(s, off);
    float mean = s * (1.0f / 256.0f);
    float c0 = v.x - mean, c1 = v.y - mean, c2 = v.z - mean, c3 = v.w - mean;
    float ss = c0*c0 + c1*c1 + c2*c2 + c3*c3;
    #pragma unroll
    for (int off = 32; off; off >>= 1) ss += __shfl_xor(ss, off);
    float inv = 1.0f / fmaxf(sqrtf(ss * (1.0f / 256.0f)), EPSF);
    float n0 = c0*inv, n1 = c1*inv, n2 = c2*inv, n3 = c3*inv;
    f16x4 h, lo;
    h[0] = (_Float16)n0; h[1] = (_Float16)n1; h[2] = (_Float16)n2; h[3] = (_Float16)n3;
    lo[0] = (_Float16)(n0 - (float)h[0]);
    lo[1] = (_Float16)(n1 - (float)h[1]);
    lo[2] = (_Float16)(n2 - (float)h[2]);
    lo[3] = (_Float16)(n3 - (float)h[3]);
    _Float16* base = xd + (size_t)row * KD + lane * 4;
    *(f16x4*)base = h;
    *(f16x4*)(base + 256) = lo;
}

// ------- Kernel 1: fp16 split-product MFMA GEMM + register-resident top-20 -------
// dot = hi.hi' + hi.lo' + lo.hi'  (lo.lo' ~ 2^-22, dropped)  => fp32-parity sim.
// block: 256 thr (4 waves). 128 rows/block, 512 cols (CSPLIT=8), col-tiles of 128.
// 32 KB LDS + 128 VGPR (launch_bounds(256,2) -- (256,4) forced 64 VGPR and spilled
// acc+lists to scratch: 13.8 GB HBM traffic, 16x regression) -> 4 blocks/CU.
#define INSERT(MM, OFF, LVR, LIR)                                       \
    while (MM) {                                                        \
        int cbit = __ffs(MM) - 1; MM &= MM - 1;                         \
        float val = __shfl(vv, cbit + OFF);                             \
        float mn = __shfl(LVR, 19);                                     \
        if (val > mn) {                                                 \
            unsigned long long ge = __ballot(LVR >= val);               \
            int pos = __popcll(ge & 0xFFFFFull);                        \
            float sv = __shfl_up(LVR, 1);                               \
            int si = __shfl_up(LIR, 1);                                 \
            int colv = colbase + cbit;                                  \
            LVR = (l < pos) ? LVR : ((l == pos) ? val : sv);            \
            LIR = (l < pos) ? LIR : ((l == pos) ? colv : si);           \
        }                                                               \
    }

__global__ __launch_bounds__(256, 2) void gemm_topk(const _Float16* __restrict__ xd,
                                                    float* __restrict__ listv,
                                                    short* __restrict__ listi) {
    __shared__ __align__(16) char As[16384];   // 128 rows x 64 k x 2B
    __shared__ __align__(16) char Bs[16384];   // 128 cols x 64 k x 2B

    const int tid = threadIdx.x;
    const int w = tid >> 6;
    const int l = tid & 63;

    const int bid = blockIdx.x;                // ((b*32 + rowblk)*8 + cs)
    const int cs = bid & 7;
    const int rowblk = (bid >> 3) & 31;
    const int b = bid >> 8;
    const int r0 = rowblk * 128;
    const size_t nbase = (size_t)b * NN;
    const _Float16* xb = xd + nbase * KD;

    float lv[32]; int li[32];
    #pragma unroll
    for (int r = 0; r < 32; ++r) { lv[r] = -1.0f; li[r] = -1; }

    // staging lane constants: one 1KB instr = 8 rows x 128 B; lane l -> row l>>3, slot l&7
    const int srow = l >> 3;
    const int sslot = l & 7;
    const int skl = (sslot ^ srow) * 8;        // pre-swizzled src k (f16 elems); row&7 == srow
    // fragment lane constants
    const int lrow = l & 31;
    const int kg2 = l >> 5;                    // k-half 0/1
    const int r7 = l & 7;                      // row&7 for both A (lrow) and B (j*32+lrow)
    const char* aRow = As + (w * 32 + lrow) * 128;
    const char* bRow = Bs + lrow * 128;

    f32x16 acc[4];

    for (int ct = 0; ct < 4; ++ct) {           // 4 col-tiles of 128
        const int c0 = cs * 512 + ct * 128;
        #pragma unroll
        for (int j = 0; j < 4; ++j)
            #pragma unroll
            for (int e = 0; e < 16; ++e) acc[j][e] = 0.0f;

        // 3-pass split product over 64-k chunks:
        // g=0: hi.hi' (aoff=q*64,     boff=q*64)
        // g=1: hi.lo' (aoff=q*64,     boff=256+q*64)
        // g=2: lo.hi' (aoff=256+q*64, boff=q*64)
        #pragma unroll
        for (int p = 0; p < 12; ++p) {
            const int g = p >> 2, q = p & 3;
            const int aoff = ((g < 2) ? 0 : 256) + q * 64;
            const int boff = ((g == 1) ? 256 : 0) + q * 64;
            __syncthreads();                   // prior readers of As/Bs done
            #pragma unroll
            for (int s = 0; s < 4; ++s) {
                const int i = w * 4 + s;       // 1KB instr index 0..15 (wave-uniform)
                const int row = i * 8 + srow;
                const _Float16* ga = xb + (size_t)(r0 + row) * KD + aoff + skl;
                __builtin_amdgcn_global_load_lds(
                    (const __attribute__((address_space(1))) void*)ga,
                    (__attribute__((address_space(3))) void*)(As + i * 1024), 16, 0, 0);
                const _Float16* gb = xb + (size_t)(c0 + row) * KD + boff + skl;
                __builtin_amdgcn_global_load_lds(
                    (const __attribute__((address_space(1))) void*)gb,
                    (__attribute__((address_space(3))) void*)(Bs + i * 1024), 16, 0, 0);
            }
            __syncthreads();                   // loads drained
            #pragma unroll
            for (int ks = 0; ks < 4; ++ks) {
                const int koff = ((ks * 2 + kg2) ^ r7) << 4;
                f16x8 a = *(const f16x8*)(aRow + koff);
                #pragma unroll
                for (int j = 0; j < 4; ++j) {
                    f16x8 bj = *(const f16x8*)(bRow + j * 4096 + koff);
                    acc[j] = __builtin_amdgcn_mfma_f32_32x32x16_f16(a, bj, acc[j], 0, 0, 0);
                }
            }
        }

        // ---- per-tile top-k scan (register lists, all-lane parallel insert) ----
        #pragma unroll
        for (int rg = 0; rg < 16; ++rg) {
            const int rA = (rg & 3) + 8 * (rg >> 2);      // compile-time
            const int rB = rA + 4;
            const int rowl = rA + ((l >> 5) << 2);
            const int grow = r0 + w * 32 + rowl;          // batch-local row
            float thrA = fmaxf(__shfl(lv[rA], 19), 0.0f);
            float thrB = fmaxf(__shfl(lv[rB], 19), 0.0f);
            float thr = (l < 32) ? thrA : thrB;
            #pragma unroll
            for (int j = 0; j < 4; ++j) {
                const int colbase = c0 + j * 32;
                float vv = fmaxf(acc[j][rg] * (1.0f / 256.0f), 0.0f);
                if (colbase + (l & 31) == grow) vv = 0.0f;  // zero diagonal
                unsigned long long m = __ballot(vv > thr);
                unsigned int mA = (unsigned int)m;
                unsigned int mB = (unsigned int)(m >> 32);
                INSERT(mA, 0, lv[rA], li[rA])
                INSERT(mB, 32, lv[rB], li[rB])
            }
        }
    }

    // write partial lists (20 per row per split)
    #pragma unroll
    for (int r = 0; r < 32; ++r) {
        size_t grow = nbase + r0 + w * 32 + r;
        size_t basep = (grow * CSPLIT + cs) * KTOP;
        if (l < KTOP) {
            listv[basep + l] = fmaxf(lv[r], 0.0f);   // dummies -> 0
            listi[basep + l] = (short)li[r];         // dummies -> -1 (never scattered)
        }
    }
}

// ------- Kernel 2: 8-way rank-merge + double row-normalize + write -------
__global__ __launch_bounds__(256) void merge_kernel(const float* __restrict__ listv,
                                                    const short* __restrict__ listi,
                                                    float* __restrict__ out) {
    __shared__ float ldsv[4][NCAND];
    __shared__ int   ldsi[4][NCAND];
    __shared__ float selv[4][KTOP];
    __shared__ int   seli[4][KTOP];
    const int tid = threadIdx.x;
    const int wv = tid >> 6;
    const int l = tid & 63;
    const size_t gr = (size_t)blockIdx.x * 4 + wv;    // global row 0..16383

    for (int q = l; q < NCAND; q += 64) {
        ldsv[wv][q] = listv[gr * NCAND + q];
        ldsi[wv][q] = (int)listi[gr * NCAND + q];
    }
    __syncthreads();

    // rank-select top-20 of 160: strict total order (val desc, idx asc, slot asc)
    const int q0 = l, q1 = l + 64, q2 = l + 128;
    float v0 = ldsv[wv][q0];                 int i0 = ldsi[wv][q0];
    float v1 = ldsv[wv][q1];                 int i1 = ldsi[wv][q1];
    float v2 = (l < 32) ? ldsv[wv][q2] : -2.0f;
    int   i2 = (l < 32) ? ldsi[wv][q2] : 0x7fffffff;
    int rank0 = 0, rank1 = 0, rank2 = 0;
    for (int p = 0; p < NCAND; ++p) {
        float vp = ldsv[wv][p]; int ip = ldsi[wv][p];
        rank0 += ((vp > v0) || (vp == v0 && (ip < i0 || (ip == i0 && p < q0)))) ? 1 : 0;
        rank1 += ((vp > v1) || (vp == v1 && (ip < i1 || (ip == i1 && p < q1)))) ? 1 : 0;
        rank2 += ((vp > v2) || (vp == v2 && (ip < i2 || (ip == i2 && p < q2)))) ? 1 : 0;
    }
    if (rank0 < KTOP) { selv[wv][rank0] = v0; seli[wv][rank0] = i0; }
    if (rank1 < KTOP) { selv[wv][rank1] = v1; seli[wv][rank1] = i1; }
    if (l < 32 && rank2 < KTOP) { selv[wv][rank2] = v2; seli[wv][rank2] = i2; }
    __syncthreads();

    // double row-normalize (matches reference: /max(sum,eps) twice)
    float wval = (l < KTOP) ? selv[wv][l] : 0.0f;
    int   widx = (l < KTOP) ? seli[wv][l] : -1;
    float s1 = wval;
    #pragma unroll
    for (int off = 32; off; off >>= 1) s1 += __shfl_xor(s1, off);
    float w1 = wval / fmaxf(s1, EPSF);
    float s2 = (l < KTOP) ? w1 : 0.0f;
    #pragma unroll
    for (int off = 32; off; off >>= 1) s2 += __shfl_xor(s2, off);
    float wf = w1 / fmaxf(s2, EPSF);

    // zero the 4 output rows (coalesced float4), then scatter 20 values per row
    float4* obase = reinterpret_cast<float4*>(out + (size_t)blockIdx.x * 4 * NN);
    float4 z = make_float4(0.f, 0.f, 0.f, 0.f);
    for (int i = tid; i < 4 * (NN / 4); i += 256) obase[i] = z;
    __syncthreads();
    if (l < KTOP && widx >= 0) out[gr * NN + widx] = wf;
}

extern "C" void kernel_launch(void* const* d_in, const int* in_sizes, int n_in,
                              void* d_out, int out_size, void* d_ws, size_t ws_size,
                              hipStream_t stream) {
    const float* hist = (const float*)d_in[0];
    // d_in[1] = mask [B,N] — all ones in this problem; ignored.
    char* ws = (char*)d_ws;
    const size_t xdBytes = (size_t)NB * NN * KD * sizeof(_Float16);        // 16.78 MB
    const size_t lvBytes = (size_t)NB * NN * NCAND * sizeof(float);        // 10.49 MB
    _Float16* xd = (_Float16*)ws;
    float* listv = (float*)(ws + xdBytes);
    short* listi = (short*)(ws + xdBytes + lvBytes);                        // 5.24 MB
    float* out = (float*)d_out;

    stats_split<<<NB * NN, 64, 0, stream>>>(hist, xd);
    gemm_topk<<<NB * 32 * CSPLIT, 256, 0, stream>>>(xd, listv, listi);
    merge_kernel<<<NB * NN / 4, 256, 0, stream>>>(listv, listi, out);
}

// Round 7
// 483.774 us; speedup vs baseline: 23.9698x; 2.2043x over previous
//
#include <hip/hip_runtime.h>
#include <cstdint>

#define NB 4
#define NN 4096
#define LL 256
#define KTOP 20
#define EPSF 1e-6f
#define CSPLIT 8
#define NCAND (CSPLIT * KTOP)   // 160
#define KD 512          // storage: [hi(256) | lo(256)] fp16 per row

typedef _Float16 f16x8 __attribute__((ext_vector_type(8)));
typedef _Float16 f16x4 __attribute__((ext_vector_type(4)));
typedef float f32x16 __attribute__((ext_vector_type(16)));

// ---------------- Kernel 0: per-row stats + fp16 hi/lo split ----------------
__global__ __launch_bounds__(64) void stats_split(const float* __restrict__ hist,
                                                  _Float16* __restrict__ xd) {
    int row = blockIdx.x;              // 0 .. B*N-1
    int lane = threadIdx.x;            // 0 .. 63
    float4 v = reinterpret_cast<const float4*>(hist + (size_t)row * LL)[lane];
    float s = v.x + v.y + v.z + v.w;
    #pragma unroll
    for (int off = 32; off; off >>= 1) s += __shfl_xor(s, off);
    float mean = s * (1.0f / 256.0f);
    float c0 = v.x - mean, c1 = v.y - mean, c2 = v.z - mean, c3 = v.w - mean;
    float ss = c0*c0 + c1*c1 + c2*c2 + c3*c3;
    #pragma unroll
    for (int off = 32; off; off >>= 1) ss += __shfl_xor(ss, off);
    float inv = 1.0f / fmaxf(sqrtf(ss * (1.0f / 256.0f)), EPSF);
    float n0 = c0*inv, n1 = c1*inv, n2 = c2*inv, n3 = c3*inv;
    f16x4 h, lo;
    h[0] = (_Float16)n0; h[1] = (_Float16)n1; h[2] = (_Float16)n2; h[3] = (_Float16)n3;
    lo[0] = (_Float16)(n0 - (float)h[0]);
    lo[1] = (_Float16)(n1 - (float)h[1]);
    lo[2] = (_Float16)(n2 - (float)h[2]);
    lo[3] = (_Float16)(n3 - (float)h[3]);
    _Float16* base = xd + (size_t)row * KD + lane * 4;
    *(f16x4*)base = h;
    *(f16x4*)(base + 256) = lo;
}

// ------- Kernel 1: fp16 split-product MFMA GEMM + per-lane sorted-key top-20 -------
// dot = hi.hi' + hi.lo' + lo.hi' (fp32-parity). Block: 256 thr (4 waves),
// 128 rows, 512 cols (CSPLIT=8), col-tiles of 64 (acc = 2 x f32x16 = 32 regs).
// Selection: per 64-col tile, transpose sim to LDS; lane owns (row = l&31,
// col-half = l>>5); top-20 kept as sorted u64 keys (valbits<<32 | 4095-col),
// branch-free insert k[q] = max(k[q], min(k[q-1], key)) via f64 min/max
// (keys are positive-f64 bit patterns -> f64 order == u64 order).
__global__ __launch_bounds__(256, 4) void gemm_topk(const _Float16* __restrict__ xd,
                                                    float* __restrict__ listv,
                                                    short* __restrict__ listi) {
    __shared__ __align__(16) char smem[24576];
    char* As = smem;                 // 16 KB: 128 rows x 64 k x 2B
    char* Bs = smem + 16384;         //  8 KB:  64 cols x 64 k x 2B

    const int tid = threadIdx.x;
    const int w = tid >> 6;
    const int l = tid & 63;
    const int h = l >> 5;                       // col-half for selection
    const int r = l & 31;                       // owned row (wave-local)

    float* scr = reinterpret_cast<float*>(smem + w * 4608);  // 32 rows x 36 floats

    const int bid = blockIdx.x;                 // ((b*32 + rowblk)*8 + cs)
    const int cs = bid & 7;
    const int rowblk = (bid >> 3) & 31;
    const int b = bid >> 8;
    const int r0 = rowblk * 128;
    const size_t nbase = (size_t)b * NN;
    const _Float16* xb = xd + nbase * KD;

    double k[KTOP];
    #pragma unroll
    for (int q = 0; q < KTOP; ++q) k[q] = 0.0;

    // staging lane constants: one 1KB instr = 8 rows x 128 B
    const int srow = l >> 3;
    const int sslot = l & 7;
    const int skl = (sslot ^ srow) * 8;         // pre-swizzled src k (f16 elems)
    // fragment lane constants
    const int r7 = l & 7;
    const char* aRow = As + (w * 32 + r) * 128;
    const char* bRow = Bs + r * 128;

    f32x16 acc[2];

    for (int ct = 0; ct < 8; ++ct) {            // 8 col-tiles of 64
        const int c0 = cs * 512 + ct * 64;
        #pragma unroll
        for (int j = 0; j < 2; ++j)
            #pragma unroll
            for (int e = 0; e < 16; ++e) acc[j][e] = 0.0f;

        // 3-pass split product over 64-k chunks:
        // g=0: hi.hi'  g=1: hi.lo'  g=2: lo.hi'
        #pragma unroll
        for (int p = 0; p < 12; ++p) {
            const int g = p >> 2, q = p & 3;
            const int aoff = ((g < 2) ? 0 : 256) + q * 64;
            const int boff = ((g == 1) ? 256 : 0) + q * 64;
            __syncthreads();                    // prior readers of As/Bs/scr done
            #pragma unroll
            for (int s = 0; s < 4; ++s) {       // A: 16 instrs, 4/wave
                const int i = w * 4 + s;
                const int row = i * 8 + srow;
                const _Float16* ga = xb + (size_t)(r0 + row) * KD + aoff + skl;
                __builtin_amdgcn_global_load_lds(
                    (const __attribute__((address_space(1))) void*)ga,
                    (__attribute__((address_space(3))) void*)(As + i * 1024), 16, 0, 0);
            }
            #pragma unroll
            for (int s = 0; s < 2; ++s) {       // B: 8 instrs, 2/wave
                const int i = w * 2 + s;
                const int row = i * 8 + srow;
                const _Float16* gb = xb + (size_t)(c0 + row) * KD + boff + skl;
                __builtin_amdgcn_global_load_lds(
                    (const __attribute__((address_space(1))) void*)gb,
                    (__attribute__((address_space(3))) void*)(Bs + i * 1024), 16, 0, 0);
            }
            __syncthreads();                    // loads drained
            #pragma unroll
            for (int ks = 0; ks < 4; ++ks) {
                const int koff = ((ks * 2 + h) ^ r7) << 4;
                f16x8 a = *(const f16x8*)(aRow + koff);
                #pragma unroll
                for (int j = 0; j < 2; ++j) {
                    f16x8 bj = *(const f16x8*)(bRow + j * 4096 + koff);
                    acc[j] = __builtin_amdgcn_mfma_f32_32x32x16_f16(a, bj, acc[j], 0, 0, 0);
                }
            }
        }

        __syncthreads();   // all waves' MFMA reads of As/Bs done; scr may overwrite
        // ---- per-tile selection: transpose to LDS, per-lane sorted-key scan ----
        #pragma unroll
        for (int j = 0; j < 2; ++j) {
            // write 32x32 sim values (relu, /L, zero-diag), bank-spread layout
            #pragma unroll
            for (int rg = 0; rg < 16; ++rg) {
                const int rowl = (rg & 3) + 8 * (rg >> 2) + 4 * h;
                const int col = l & 31;
                const int gg = col >> 2, e = col & 3;
                const int gp = ((gg & 3) ^ (rowl >> 3)) | (((gg >> 2) ^ (rowl & 1)) << 2);
                float v = fmaxf(acc[j][rg] * (1.0f / 256.0f), 0.0f);
                if (c0 + j * 32 + col == r0 + w * 32 + rowl) v = 0.0f;
                scr[rowl * 36 + gp * 4 + e] = v;
            }
            // read own half-row (16 values) and scan (wave-private region:
            // same-wave ds ordering suffices, no barrier)
            const float* rb = scr + r * 36;
            #pragma unroll
            for (int c4 = 0; c4 < 4; ++c4) {
                const int gp = (c4 ^ (r >> 3)) | ((h ^ (r & 1)) << 2);
                float4 vv = *(const float4*)(rb + gp * 4);
                #pragma unroll
                for (int e = 0; e < 4; ++e) {
                    float v = (e == 0) ? vv.x : (e == 1) ? vv.y : (e == 2) ? vv.z : vv.w;
                    int gcol = c0 + j * 32 + (h * 4 + c4) * 4 + e;
                    double key = __hiloint2double(__float_as_int(v), 4095 - gcol);
                    #pragma unroll
                    for (int q = KTOP - 1; q > 0; --q)
                        k[q] = fmax(k[q], fmin(k[q - 1], key));
                    k[0] = fmax(k[0], key);
                }
            }
        }
    }

    // ---- merge the two half-row lists by rank, write top-20 per (row, split) ----
    int cnt[KTOP];
    #pragma unroll
    for (int p = 0; p < KTOP; ++p) cnt[p] = 0;
    #pragma unroll
    for (int q = 0; q < KTOP; ++q) {
        int phi = __shfl_xor(__double2hiint(k[q]), 32);
        int plo = __shfl_xor(__double2loint(k[q]), 32);
        double pk = __hiloint2double(phi, plo);
        #pragma unroll
        for (int p = 0; p < KTOP; ++p) cnt[p] += (pk > k[p]) ? 1 : 0;
    }
    size_t base = ((nbase + r0 + w * 32 + r) * CSPLIT + cs) * KTOP;
    #pragma unroll
    for (int p = 0; p < KTOP; ++p) {
        int rank = p + cnt[p];
        if (rank < KTOP) {
            int hi = __double2hiint(k[p]);
            int lo = __double2loint(k[p]);
            listv[base + rank] = __int_as_float(hi);
            listi[base + rank] = (short)(4095 - lo);
        }
    }
}

// ------- Kernel 2: 8-way rank-merge + double row-normalize + write -------
__global__ __launch_bounds__(256) void merge_kernel(const float* __restrict__ listv,
                                                    const short* __restrict__ listi,
                                                    float* __restrict__ out) {
    __shared__ float ldsv[4][NCAND];
    __shared__ int   ldsi[4][NCAND];
    __shared__ float selv[4][KTOP];
    __shared__ int   seli[4][KTOP];
    const int tid = threadIdx.x;
    const int wv = tid >> 6;
    const int l = tid & 63;
    const size_t gr = (size_t)blockIdx.x * 4 + wv;    // global row 0..16383

    for (int q = l; q < NCAND; q += 64) {
        ldsv[wv][q] = listv[gr * NCAND + q];
        ldsi[wv][q] = (int)listi[gr * NCAND + q];
    }
    __syncthreads();

    // rank-select top-20 of 160: strict total order (val desc, idx asc, slot asc)
    const int q0 = l, q1 = l + 64, q2 = l + 128;
    float v0 = ldsv[wv][q0];                 int i0 = ldsi[wv][q0];
    float v1 = ldsv[wv][q1];                 int i1 = ldsi[wv][q1];
    float v2 = (l < 32) ? ldsv[wv][q2] : -2.0f;
    int   i2 = (l < 32) ? ldsi[wv][q2] : 0x7fffffff;
    int rank0 = 0, rank1 = 0, rank2 = 0;
    for (int p = 0; p < NCAND; ++p) {
        float vp = ldsv[wv][p]; int ip = ldsi[wv][p];
        rank0 += ((vp > v0) || (vp == v0 && (ip < i0 || (ip == i0 && p < q0)))) ? 1 : 0;
        rank1 += ((vp > v1) || (vp == v1 && (ip < i1 || (ip == i1 && p < q1)))) ? 1 : 0;
        rank2 += ((vp > v2) || (vp == v2 && (ip < i2 || (ip == i2 && p < q2)))) ? 1 : 0;
    }
    if (rank0 < KTOP) { selv[wv][rank0] = v0; seli[wv][rank0] = i0; }
    if (rank1 < KTOP) { selv[wv][rank1] = v1; seli[wv][rank1] = i1; }
    if (l < 32 && rank2 < KTOP) { selv[wv][rank2] = v2; seli[wv][rank2] = i2; }
    __syncthreads();

    // double row-normalize (matches reference: /max(sum,eps) twice)
    float wval = (l < KTOP) ? selv[wv][l] : 0.0f;
    int   widx = (l < KTOP) ? seli[wv][l] : -1;
    float s1 = wval;
    #pragma unroll
    for (int off = 32; off; off >>= 1) s1 += __shfl_xor(s1, off);
    float w1 = wval / fmaxf(s1, EPSF);
    float s2 = (l < KTOP) ? w1 : 0.0f;
    #pragma unroll
    for (int off = 32; off; off >>= 1) s2 += __shfl_xor(s2, off);
    float wf = w1 / fmaxf(s2, EPSF);

    // zero the 4 output rows (coalesced float4), then scatter 20 values per row
    float4* obase = reinterpret_cast<float4*>(out + (size_t)blockIdx.x * 4 * NN);
    float4 z = make_float4(0.f, 0.f, 0.f, 0.f);
    for (int i = tid; i < 4 * (NN / 4); i += 256) obase[i] = z;
    __syncthreads();
    if (l < KTOP && widx >= 0 && wval > -1.0f) out[gr * NN + widx] = wf;
}

extern "C" void kernel_launch(void* const* d_in, const int* in_sizes, int n_in,
                              void* d_out, int out_size, void* d_ws, size_t ws_size,
                              hipStream_t stream) {
    const float* hist = (const float*)d_in[0];
    // d_in[1] = mask [B,N] — all ones in this problem; ignored.
    char* ws = (char*)d_ws;
    const size_t xdBytes = (size_t)NB * NN * KD * sizeof(_Float16);        // 16.78 MB
    const size_t lvBytes = (size_t)NB * NN * NCAND * sizeof(float);        // 10.49 MB
    _Float16* xd = (_Float16*)ws;
    float* listv = (float*)(ws + xdBytes);
    short* listi = (short*)(ws + xdBytes + lvBytes);                        // 5.24 MB
    float* out = (float*)d_out;

    stats_split<<<NB * NN, 64, 0, stream>>>(hist, xd);
    gemm_topk<<<NB * 32 * CSPLIT, 256, 0, stream>>>(xd, listv, listi);
    merge_kernel<<<NB * NN / 4, 256, 0, stream>>>(listv, listi, out);
}

// Round 8
// 369.012 us; speedup vs baseline: 31.4243x; 1.3110x over previous
//
#include <hip/hip_runtime.h>
#include <cstdint>

#define NB 4
#define NN 4096
#define LL 256
#define KTOP 20
#define EPSF 1e-6f
#define CSPLIT 8
#define NCAND (CSPLIT * KTOP)   // 160
#define KD 512          // storage: [hi(256) | lo(256)] fp16 per row

typedef _Float16 f16x8 __attribute__((ext_vector_type(8)));
typedef _Float16 f16x4 __attribute__((ext_vector_type(4)));
typedef float f32x16 __attribute__((ext_vector_type(16)));

// ---------------- Kernel 0: per-row stats + fp16 hi/lo split ----------------
__global__ __launch_bounds__(64) void stats_split(const float* __restrict__ hist,
                                                  _Float16* __restrict__ xd) {
    int row = blockIdx.x;              // 0 .. B*N-1
    int lane = threadIdx.x;            // 0 .. 63
    float4 v = reinterpret_cast<const float4*>(hist + (size_t)row * LL)[lane];
    float s = v.x + v.y + v.z + v.w;
    #pragma unroll
    for (int off = 32; off; off >>= 1) s += __shfl_xor(s, off);
    float mean = s * (1.0f / 256.0f);
    float c0 = v.x - mean, c1 = v.y - mean, c2 = v.z - mean, c3 = v.w - mean;
    float ss = c0*c0 + c1*c1 + c2*c2 + c3*c3;
    #pragma unroll
    for (int off = 32; off; off >>= 1) ss += __shfl_xor(ss, off);
    float inv = 1.0f / fmaxf(sqrtf(ss * (1.0f / 256.0f)), EPSF);
    float n0 = c0*inv, n1 = c1*inv, n2 = c2*inv, n3 = c3*inv;
    f16x4 h, lo;
    h[0] = (_Float16)n0; h[1] = (_Float16)n1; h[2] = (_Float16)n2; h[3] = (_Float16)n3;
    lo[0] = (_Float16)(n0 - (float)h[0]);
    lo[1] = (_Float16)(n1 - (float)h[1]);
    lo[2] = (_Float16)(n2 - (float)h[2]);
    lo[3] = (_Float16)(n3 - (float)h[3]);
    _Float16* base = xd + (size_t)row * KD + lane * 4;
    *(f16x4*)base = h;
    *(f16x4*)(base + 256) = lo;
}

// ------- Kernel 1: fp16 split-product MFMA GEMM + per-lane sorted-key top-20 -------
// dot = hi.hi' + hi.lo' + lo.hi' (fp32-parity). Block: 256 thr (4 waves),
// 128 rows, 512 cols (CSPLIT=8), col-tiles of 64 (acc = 2 x f32x16 = 32 regs).
// Selection: per 64-col tile, transpose sim to LDS; lane owns (row = l&31,
// col-half = l>>5); top-20 kept as sorted u64 keys (valbits<<32 | 4095-col),
// branch-free insert k[q] = max(k[q], min(k[q-1], key)) via f64 min/max.
// NOTE launch_bounds(256,2): live set ~100 regs (keys 40 + acc 32 + addr);
// (256,4) capped VGPR at 64 and spilled -> 1.4 GB scratch traffic (round 7).
__global__ __launch_bounds__(256, 2) void gemm_topk(const _Float16* __restrict__ xd,
                                                    float* __restrict__ listv,
                                                    short* __restrict__ listi) {
    __shared__ __align__(16) char smem[24576];
    char* As = smem;                 // 16 KB: 128 rows x 64 k x 2B
    char* Bs = smem + 16384;         //  8 KB:  64 cols x 64 k x 2B

    const int tid = threadIdx.x;
    const int w = tid >> 6;
    const int l = tid & 63;
    const int h = l >> 5;                       // col-half for selection
    const int r = l & 31;                       // owned row (wave-local)

    float* scr = reinterpret_cast<float*>(smem + w * 4608);  // 32 rows x 36 floats

    const int bid = blockIdx.x;                 // ((b*32 + rowblk)*8 + cs)
    const int cs = bid & 7;
    const int rowblk = (bid >> 3) & 31;
    const int b = bid >> 8;
    const int r0 = rowblk * 128;
    const size_t nbase = (size_t)b * NN;
    const _Float16* xb = xd + nbase * KD;

    double k[KTOP];
    #pragma unroll
    for (int q = 0; q < KTOP; ++q) k[q] = 0.0;

    // staging lane constants: one 1KB instr = 8 rows x 128 B
    const int srow = l >> 3;
    const int sslot = l & 7;
    const int skl = (sslot ^ srow) * 8;         // pre-swizzled src k (f16 elems)
    // fragment lane constants
    const int r7 = l & 7;
    const char* aRow = As + (w * 32 + r) * 128;
    const char* bRow = Bs + r * 128;

    f32x16 acc[2];

    for (int ct = 0; ct < 8; ++ct) {            // 8 col-tiles of 64
        const int c0 = cs * 512 + ct * 64;
        #pragma unroll
        for (int j = 0; j < 2; ++j)
            #pragma unroll
            for (int e = 0; e < 16; ++e) acc[j][e] = 0.0f;

        // 3-pass split product over 64-k chunks:
        // g=0: hi.hi'  g=1: hi.lo'  g=2: lo.hi'
        #pragma unroll
        for (int p = 0; p < 12; ++p) {
            const int g = p >> 2, q = p & 3;
            const int aoff = ((g < 2) ? 0 : 256) + q * 64;
            const int boff = ((g == 1) ? 256 : 0) + q * 64;
            __syncthreads();                    // prior readers of As/Bs/scr done
            #pragma unroll
            for (int s = 0; s < 4; ++s) {       // A: 16 instrs, 4/wave
                const int i = w * 4 + s;
                const int row = i * 8 + srow;
                const _Float16* ga = xb + (size_t)(r0 + row) * KD + aoff + skl;
                __builtin_amdgcn_global_load_lds(
                    (const __attribute__((address_space(1))) void*)ga,
                    (__attribute__((address_space(3))) void*)(As + i * 1024), 16, 0, 0);
            }
            #pragma unroll
            for (int s = 0; s < 2; ++s) {       // B: 8 instrs, 2/wave
                const int i = w * 2 + s;
                const int row = i * 8 + srow;
                const _Float16* gb = xb + (size_t)(c0 + row) * KD + boff + skl;
                __builtin_amdgcn_global_load_lds(
                    (const __attribute__((address_space(1))) void*)gb,
                    (__attribute__((address_space(3))) void*)(Bs + i * 1024), 16, 0, 0);
            }
            __syncthreads();                    // loads drained
            #pragma unroll
            for (int ks = 0; ks < 4; ++ks) {
                const int koff = ((ks * 2 + h) ^ r7) << 4;
                f16x8 a = *(const f16x8*)(aRow + koff);
                #pragma unroll
                for (int j = 0; j < 2; ++j) {
                    f16x8 bj = *(const f16x8*)(bRow + j * 4096 + koff);
                    acc[j] = __builtin_amdgcn_mfma_f32_32x32x16_f16(a, bj, acc[j], 0, 0, 0);
                }
            }
        }

        __syncthreads();   // all waves' MFMA reads of As/Bs done; scr may overwrite
        // ---- per-tile selection: transpose to LDS, per-lane sorted-key scan ----
        #pragma unroll
        for (int j = 0; j < 2; ++j) {
            // write 32x32 sim values (relu, /L, zero-diag), bank-spread layout
            #pragma unroll
            for (int rg = 0; rg < 16; ++rg) {
                const int rowl = (rg & 3) + 8 * (rg >> 2) + 4 * h;
                const int col = l & 31;
                const int gg = col >> 2, e = col & 3;
                const int gp = ((gg & 3) ^ (rowl >> 3)) | (((gg >> 2) ^ (rowl & 1)) << 2);
                float v = fmaxf(acc[j][rg] * (1.0f / 256.0f), 0.0f);
                if (c0 + j * 32 + col == r0 + w * 32 + rowl) v = 0.0f;
                scr[rowl * 36 + gp * 4 + e] = v;
            }
            // read own half-row (16 values) and scan (wave-private region:
            // same-wave ds ordering suffices, no barrier)
            const float* rb = scr + r * 36;
            #pragma unroll
            for (int c4 = 0; c4 < 4; ++c4) {
                const int gp = (c4 ^ (r >> 3)) | ((h ^ (r & 1)) << 2);
                float4 vv = *(const float4*)(rb + gp * 4);
                #pragma unroll
                for (int e = 0; e < 4; ++e) {
                    float v = (e == 0) ? vv.x : (e == 1) ? vv.y : (e == 2) ? vv.z : vv.w;
                    int gcol = c0 + j * 32 + (h * 4 + c4) * 4 + e;
                    double key = __hiloint2double(__float_as_int(v), 4095 - gcol);
                    #pragma unroll
                    for (int q = KTOP - 1; q > 0; --q)
                        k[q] = fmax(k[q], fmin(k[q - 1], key));
                    k[0] = fmax(k[0], key);
                }
            }
        }
    }

    // ---- merge the two half-row lists by rank, write top-20 per (row, split) ----
    int cnt[KTOP];
    #pragma unroll
    for (int p = 0; p < KTOP; ++p) cnt[p] = 0;
    #pragma unroll
    for (int q = 0; q < KTOP; ++q) {
        int phi = __shfl_xor(__double2hiint(k[q]), 32);
        int plo = __shfl_xor(__double2loint(k[q]), 32);
        double pk = __hiloint2double(phi, plo);
        #pragma unroll
        for (int p = 0; p < KTOP; ++p) cnt[p] += (pk > k[p]) ? 1 : 0;
    }
    size_t base = ((nbase + r0 + w * 32 + r) * CSPLIT + cs) * KTOP;
    #pragma unroll
    for (int p = 0; p < KTOP; ++p) {
        int rank = p + cnt[p];
        if (rank < KTOP) {
            int hi = __double2hiint(k[p]);
            int lo = __double2loint(k[p]);
            listv[base + rank] = __int_as_float(hi);
            listi[base + rank] = (short)(4095 - lo);
        }
    }
}

// ------- Kernel 2: 8-way rank-merge + double row-normalize + write -------
__global__ __launch_bounds__(256) void merge_kernel(const float* __restrict__ listv,
                                                    const short* __restrict__ listi,
                                                    float* __restrict__ out) {
    __shared__ float ldsv[4][NCAND];
    __shared__ int   ldsi[4][NCAND];
    __shared__ float selv[4][KTOP];
    __shared__ int   seli[4][KTOP];
    const int tid = threadIdx.x;
    const int wv = tid >> 6;
    const int l = tid & 63;
    const size_t gr = (size_t)blockIdx.x * 4 + wv;    // global row 0..16383

    for (int q = l; q < NCAND; q += 64) {
        ldsv[wv][q] = listv[gr * NCAND + q];
        ldsi[wv][q] = (int)listi[gr * NCAND + q];
    }
    __syncthreads();

    // rank-select top-20 of 160: strict total order (val desc, idx asc, slot asc)
    const int q0 = l, q1 = l + 64, q2 = l + 128;
    float v0 = ldsv[wv][q0];                 int i0 = ldsi[wv][q0];
    float v1 = ldsv[wv][q1];                 int i1 = ldsi[wv][q1];
    float v2 = (l < 32) ? ldsv[wv][q2] : -2.0f;
    int   i2 = (l < 32) ? ldsi[wv][q2] : 0x7fffffff;
    int rank0 = 0, rank1 = 0, rank2 = 0;
    for (int p = 0; p < NCAND; ++p) {
        float vp = ldsv[wv][p]; int ip = ldsi[wv][p];
        rank0 += ((vp > v0) || (vp == v0 && (ip < i0 || (ip == i0 && p < q0)))) ? 1 : 0;
        rank1 += ((vp > v1) || (vp == v1 && (ip < i1 || (ip == i1 && p < q1)))) ? 1 : 0;
        rank2 += ((vp > v2) || (vp == v2 && (ip < i2 || (ip == i2 && p < q2)))) ? 1 : 0;
    }
    if (rank0 < KTOP) { selv[wv][rank0] = v0; seli[wv][rank0] = i0; }
    if (rank1 < KTOP) { selv[wv][rank1] = v1; seli[wv][rank1] = i1; }
    if (l < 32 && rank2 < KTOP) { selv[wv][rank2] = v2; seli[wv][rank2] = i2; }
    __syncthreads();

    // double row-normalize (matches reference: /max(sum,eps) twice)
    float wval = (l < KTOP) ? selv[wv][l] : 0.0f;
    int   widx = (l < KTOP) ? seli[wv][l] : -1;
    float s1 = wval;
    #pragma unroll
    for (int off = 32; off; off >>= 1) s1 += __shfl_xor(s1, off);
    float w1 = wval / fmaxf(s1, EPSF);
    float s2 = (l < KTOP) ? w1 : 0.0f;
    #pragma unroll
    for (int off = 32; off; off >>= 1) s2 += __shfl_xor(s2, off);
    float wf = w1 / fmaxf(s2, EPSF);

    // zero the 4 output rows (coalesced float4), then scatter 20 values per row
    float4* obase = reinterpret_cast<float4*>(out + (size_t)blockIdx.x * 4 * NN);
    float4 z = make_float4(0.f, 0.f, 0.f, 0.f);
    for (int i = tid; i < 4 * (NN / 4); i += 256) obase[i] = z;
    __syncthreads();
    if (l < KTOP && widx >= 0 && wval > -1.0f) out[gr * NN + widx] = wf;
}

extern "C" void kernel_launch(void* const* d_in, const int* in_sizes, int n_in,
                              void* d_out, int out_size, void* d_ws, size_t ws_size,
                              hipStream_t stream) {
    const float* hist = (const float*)d_in[0];
    // d_in[1] = mask [B,N] — all ones in this problem; ignored.
    char* ws = (char*)d_ws;
    const size_t xdBytes = (size_t)NB * NN * KD * sizeof(_Float16);        // 16.78 MB
    const size_t lvBytes = (size_t)NB * NN * NCAND * sizeof(float);        // 10.49 MB
    _Float16* xd = (_Float16*)ws;
    float* listv = (float*)(ws + xdBytes);
    short* listi = (short*)(ws + xdBytes + lvBytes);                        // 5.24 MB
    float* out = (float*)d_out;

    stats_split<<<NB * NN, 64, 0, stream>>>(hist, xd);
    gemm_topk<<<NB * 32 * CSPLIT, 256, 0, stream>>>(xd, listv, listi);
    merge_kernel<<<NB * NN / 4, 256, 0, stream>>>(listv, listi, out);
}

// Round 9
// 319.546 us; speedup vs baseline: 36.2888x; 1.1548x over previous
//
#include <hip/hip_runtime.h>
#include <cstdint>

#define NB 4
#define NN 4096
#define LL 256
#define KTOP 20
#define EPSF 1e-6f
#define CSPLIT 8
#define NCAND (CSPLIT * KTOP)   // 160
#define KD 512          // storage: [hi(256) | lo(256)] fp16 per row

typedef _Float16 f16x8 __attribute__((ext_vector_type(8)));
typedef _Float16 f16x4 __attribute__((ext_vector_type(4)));
typedef float f32x16 __attribute__((ext_vector_type(16)));

// ---------------- Kernel 0: per-row stats + fp16 hi/lo split ----------------
__global__ __launch_bounds__(64) void stats_split(const float* __restrict__ hist,
                                                  _Float16* __restrict__ xd) {
    int row = blockIdx.x;              // 0 .. B*N-1
    int lane = threadIdx.x;            // 0 .. 63
    float4 v = reinterpret_cast<const float4*>(hist + (size_t)row * LL)[lane];
    float s = v.x + v.y + v.z + v.w;
    #pragma unroll
    for (int off = 32; off; off >>= 1) s += __shfl_xor(s, off);
    float mean = s * (1.0f / 256.0f);
    float c0 = v.x - mean, c1 = v.y - mean, c2 = v.z - mean, c3 = v.w - mean;
    float ss = c0*c0 + c1*c1 + c2*c2 + c3*c3;
    #pragma unroll
    for (int off = 32; off; off >>= 1) ss += __shfl_xor(ss, off);
    float inv = 1.0f / fmaxf(sqrtf(ss * (1.0f / 256.0f)), EPSF);
    float n0 = c0*inv, n1 = c1*inv, n2 = c2*inv, n3 = c3*inv;
    f16x4 h, lo;
    h[0] = (_Float16)n0; h[1] = (_Float16)n1; h[2] = (_Float16)n2; h[3] = (_Float16)n3;
    lo[0] = (_Float16)(n0 - (float)h[0]);
    lo[1] = (_Float16)(n1 - (float)h[1]);
    lo[2] = (_Float16)(n2 - (float)h[2]);
    lo[3] = (_Float16)(n3 - (float)h[3]);
    _Float16* base = xd + (size_t)row * KD + lane * 4;
    *(f16x4*)base = h;
    *(f16x4*)(base + 256) = lo;
}

// ------- Kernel 1: fp16 split-product MFMA GEMM + per-lane sorted-key top-20 -------
// dot = hi.hi' + hi.lo' + lo.hi' (fp32-parity). Block: 256 thr (4 waves),
// 128 rows, 512 cols (CSPLIT=8), col-tiles of 64.
// Joint staging: As = 128 rows x [hi_q(128B) | lo_q(128B)] (32 KB), Bs = 64
// cols x one half (8 KB). Per quarter: {stage A+Bhi; 16 MFMA (Ahi.Bhi +
// Alo.Bhi); stage Blo; 8 MFMA (Ahi.Blo)} -> 8 drains/tile vs 12, staged bytes
// 192KB vs 288KB, A-hi/B-hi fetched once. LDS 40KB -> 4 blocks/CU.
// Selection: per 64-col tile, transpose sim to LDS; lane owns (row = l&31,
// col-half = l>>5); top-20 kept as sorted u64 keys (valbits<<32 | 4095-col),
// branch-free insert k[q] = max(k[q], min(k[q-1], key)) via f64 min/max.
// NOTE launch_bounds(256,2): (256,4) capped VGPR at 64 -> spill (rounds 5,7).
__global__ __launch_bounds__(256, 2) void gemm_topk(const _Float16* __restrict__ xd,
                                                    float* __restrict__ listv,
                                                    short* __restrict__ listi) {
    __shared__ __align__(16) char smem[40960];
    char* As = smem;                 // 32 KB: 128 rows x 256 B ([hi|lo] swizzled)
    char* Bs = smem + 32768;         //  8 KB:  64 cols x 128 B (one half, swizzled)

    const int tid = threadIdx.x;
    const int w = tid >> 6;
    const int l = tid & 63;
    const int h = l >> 5;                       // col-half / C-row-half
    const int r = l & 31;                       // owned row (wave-local)

    float* scr = reinterpret_cast<float*>(smem + w * 4608);  // 32 rows x 36 floats (aliases As)

    // XCD-chunked swizzle (grid 1024, %8==0 -> bijective): blocks sharing an
    // A-panel (8 cs) land on one XCD's L2.
    const int phys = blockIdx.x;
    const int bid = (phys & 7) * 128 + (phys >> 3);
    const int cs = bid & 7;
    const int rowblk = (bid >> 3) & 31;
    const int b = bid >> 8;
    const int r0 = rowblk * 128;
    const size_t nbase = (size_t)b * NN;
    const _Float16* xb = xd + nbase * KD;

    double k[KTOP];
    #pragma unroll
    for (int q = 0; q < KTOP; ++q) k[q] = 0.0;

    // staging lane constants
    const int s7 = l & 7;
    const int ahalf = (l >> 3) & 1;             // A: lane covers hi (0) or lo (1) slot
    const int arow4 = l >> 4;                   // A: row within the 4 rows of one 1KB instr
    const int bcol8 = l >> 3;                   // B: col within the 8 cols of one 1KB instr
    // fragment lane constants
    const int r7 = l & 7;
    const char* aRow = As + (w * 32 + r) * 256;
    const char* bRow = Bs + r * 128;

    f32x16 acc[2];

    for (int ct = 0; ct < 8; ++ct) {            // 8 col-tiles of 64
        const int c0 = cs * 512 + ct * 64;
        #pragma unroll
        for (int j = 0; j < 2; ++j)
            #pragma unroll
            for (int e = 0; e < 16; ++e) acc[j][e] = 0.0f;

        #pragma unroll
        for (int q = 0; q < 4; ++q) {           // 4 k-quarters of 64
            __syncthreads();                    // prior readers of As/Bs/scr done
            // stage A quarter q, both halves: 32 instrs of 1KB (4 rows x 256B), 8/wave
            #pragma unroll
            for (int s = 0; s < 8; ++s) {
                const int i = w * 8 + s;
                const int row = i * 4 + arow4;
                const _Float16* ga = xb + (size_t)(r0 + row) * KD
                                   + ahalf * 256 + q * 64 + ((s7 ^ (row & 7)) << 3);
                __builtin_amdgcn_global_load_lds(
                    (const __attribute__((address_space(1))) void*)ga,
                    (__attribute__((address_space(3))) void*)(As + i * 1024), 16, 0, 0);
            }
            // stage B-hi quarter q: 8 instrs of 1KB (8 cols x 128B), 2/wave
            #pragma unroll
            for (int s = 0; s < 2; ++s) {
                const int i = w * 2 + s;
                const int col = i * 8 + bcol8;
                const _Float16* gb = xb + (size_t)(c0 + col) * KD
                                   + q * 64 + ((s7 ^ (col & 7)) << 3);
                __builtin_amdgcn_global_load_lds(
                    (const __attribute__((address_space(1))) void*)gb,
                    (__attribute__((address_space(3))) void*)(Bs + i * 1024), 16, 0, 0);
            }
            __syncthreads();                    // loads drained
            __builtin_amdgcn_s_setprio(1);
            #pragma unroll
            for (int ks = 0; ks < 4; ++ks) {    // Ahi.Bhi + Alo.Bhi : 16 MFMA
                const int koff = ((ks * 2 + h) ^ r7) << 4;
                f16x8 ah = *(const f16x8*)(aRow + koff);
                f16x8 al = *(const f16x8*)(aRow + 128 + koff);
                #pragma unroll
                for (int j = 0; j < 2; ++j) {
                    f16x8 bj = *(const f16x8*)(bRow + j * 4096 + koff);
                    acc[j] = __builtin_amdgcn_mfma_f32_32x32x16_f16(ah, bj, acc[j], 0, 0, 0);
                    acc[j] = __builtin_amdgcn_mfma_f32_32x32x16_f16(al, bj, acc[j], 0, 0, 0);
                }
            }
            __builtin_amdgcn_s_setprio(0);
            __syncthreads();                    // Bs readers done
            // stage B-lo quarter q
            #pragma unroll
            for (int s = 0; s < 2; ++s) {
                const int i = w * 2 + s;
                const int col = i * 8 + bcol8;
                const _Float16* gb = xb + (size_t)(c0 + col) * KD
                                   + 256 + q * 64 + ((s7 ^ (col & 7)) << 3);
                __builtin_amdgcn_global_load_lds(
                    (const __attribute__((address_space(1))) void*)gb,
                    (__attribute__((address_space(3))) void*)(Bs + i * 1024), 16, 0, 0);
            }
            __syncthreads();                    // loads drained
            __builtin_amdgcn_s_setprio(1);
            #pragma unroll
            for (int ks = 0; ks < 4; ++ks) {    // Ahi.Blo : 8 MFMA
                const int koff = ((ks * 2 + h) ^ r7) << 4;
                f16x8 ah = *(const f16x8*)(aRow + koff);
                #pragma unroll
                for (int j = 0; j < 2; ++j) {
                    f16x8 bj = *(const f16x8*)(bRow + j * 4096 + koff);
                    acc[j] = __builtin_amdgcn_mfma_f32_32x32x16_f16(ah, bj, acc[j], 0, 0, 0);
                }
            }
            __builtin_amdgcn_s_setprio(0);
        }

        __syncthreads();   // all waves' MFMA reads of As/Bs done; scr may overwrite
        // ---- per-tile selection: transpose to LDS, per-lane sorted-key scan ----
        #pragma unroll
        for (int j = 0; j < 2; ++j) {
            // write 32x32 sim values (relu, /L, zero-diag), bank-spread layout
            #pragma unroll
            for (int rg = 0; rg < 16; ++rg) {
                const int rowl = (rg & 3) + 8 * (rg >> 2) + 4 * h;
                const int col = l & 31;
                const int gg = col >> 2, e = col & 3;
                const int gp = ((gg & 3) ^ (rowl >> 3)) | (((gg >> 2) ^ (rowl & 1)) << 2);
                float v = fmaxf(acc[j][rg] * (1.0f / 256.0f), 0.0f);
                if (c0 + j * 32 + col == r0 + w * 32 + rowl) v = 0.0f;
                scr[rowl * 36 + gp * 4 + e] = v;
            }
            // read own half-row (16 values) and scan (wave-private region:
            // same-wave ds ordering suffices, no barrier)
            const float* rb = scr + r * 36;
            #pragma unroll
            for (int c4 = 0; c4 < 4; ++c4) {
                const int gp = (c4 ^ (r >> 3)) | ((h ^ (r & 1)) << 2);
                float4 vv = *(const float4*)(rb + gp * 4);
                #pragma unroll
                for (int e = 0; e < 4; ++e) {
                    float v = (e == 0) ? vv.x : (e == 1) ? vv.y : (e == 2) ? vv.z : vv.w;
                    int gcol = c0 + j * 32 + (h * 4 + c4) * 4 + e;
                    double key = __hiloint2double(__float_as_int(v), 4095 - gcol);
                    #pragma unroll
                    for (int q = KTOP - 1; q > 0; --q)
                        k[q] = fmax(k[q], fmin(k[q - 1], key));
                    k[0] = fmax(k[0], key);
                }
            }
        }
    }

    // ---- merge the two half-row lists by rank, write top-20 per (row, split) ----
    int cnt[KTOP];
    #pragma unroll
    for (int p = 0; p < KTOP; ++p) cnt[p] = 0;
    #pragma unroll
    for (int q = 0; q < KTOP; ++q) {
        int phi = __shfl_xor(__double2hiint(k[q]), 32);
        int plo = __shfl_xor(__double2loint(k[q]), 32);
        double pk = __hiloint2double(phi, plo);
        #pragma unroll
        for (int p = 0; p < KTOP; ++p) cnt[p] += (pk > k[p]) ? 1 : 0;
    }
    size_t base = ((nbase + r0 + w * 32 + r) * CSPLIT + cs) * KTOP;
    #pragma unroll
    for (int p = 0; p < KTOP; ++p) {
        int rank = p + cnt[p];
        if (rank < KTOP) {
            int hi = __double2hiint(k[p]);
            int lo = __double2loint(k[p]);
            listv[base + rank] = __int_as_float(hi);
            listi[base + rank] = (short)(4095 - lo);
        }
    }
}

// ------- Kernel 2: 8-way rank-merge + double row-normalize + write -------
__global__ __launch_bounds__(256) void merge_kernel(const float* __restrict__ listv,
                                                    const short* __restrict__ listi,
                                                    float* __restrict__ out) {
    __shared__ float ldsv[4][NCAND];
    __shared__ int   ldsi[4][NCAND];
    __shared__ float selv[4][KTOP];
    __shared__ int   seli[4][KTOP];
    const int tid = threadIdx.x;
    const int wv = tid >> 6;
    const int l = tid & 63;
    const size_t gr = (size_t)blockIdx.x * 4 + wv;    // global row 0..16383

    for (int q = l; q < NCAND; q += 64) {
        ldsv[wv][q] = listv[gr * NCAND + q];
        ldsi[wv][q] = (int)listi[gr * NCAND + q];
    }
    __syncthreads();

    // rank-select top-20 of 160: strict total order (val desc, idx asc, slot asc)
    const int q0 = l, q1 = l + 64, q2 = l + 128;
    float v0 = ldsv[wv][q0];                 int i0 = ldsi[wv][q0];
    float v1 = ldsv[wv][q1];                 int i1 = ldsi[wv][q1];
    float v2 = (l < 32) ? ldsv[wv][q2] : -2.0f;
    int   i2 = (l < 32) ? ldsi[wv][q2] : 0x7fffffff;
    int rank0 = 0, rank1 = 0, rank2 = 0;
    for (int p = 0; p < NCAND; ++p) {
        float vp = ldsv[wv][p]; int ip = ldsi[wv][p];
        rank0 += ((vp > v0) || (vp == v0 && (ip < i0 || (ip == i0 && p < q0)))) ? 1 : 0;
        rank1 += ((vp > v1) || (vp == v1 && (ip < i1 || (ip == i1 && p < q1)))) ? 1 : 0;
        rank2 += ((vp > v2) || (vp == v2 && (ip < i2 || (ip == i2 && p < q2)))) ? 1 : 0;
    }
    if (rank0 < KTOP) { selv[wv][rank0] = v0; seli[wv][rank0] = i0; }
    if (rank1 < KTOP) { selv[wv][rank1] = v1; seli[wv][rank1] = i1; }
    if (l < 32 && rank2 < KTOP) { selv[wv][rank2] = v2; seli[wv][rank2] = i2; }
    __syncthreads();

    // double row-normalize (matches reference: /max(sum,eps) twice)
    float wval = (l < KTOP) ? selv[wv][l] : 0.0f;
    int   widx = (l < KTOP) ? seli[wv][l] : -1;
    float s1 = wval;
    #pragma unroll
    for (int off = 32; off; off >>= 1) s1 += __shfl_xor(s1, off);
    float w1 = wval / fmaxf(s1, EPSF);
    float s2 = (l < KTOP) ? w1 : 0.0f;
    #pragma unroll
    for (int off = 32; off; off >>= 1) s2 += __shfl_xor(s2, off);
    float wf = w1 / fmaxf(s2, EPSF);

    // zero the 4 output rows (coalesced float4), then scatter 20 values per row
    float4* obase = reinterpret_cast<float4*>(out + (size_t)blockIdx.x * 4 * NN);
    float4 z = make_float4(0.f, 0.f, 0.f, 0.f);
    for (int i = tid; i < 4 * (NN / 4); i += 256) obase[i] = z;
    __syncthreads();
    if (l < KTOP && widx >= 0 && wval > -1.0f) out[gr * NN + widx] = wf;
}

extern "C" void kernel_launch(void* const* d_in, const int* in_sizes, int n_in,
                              void* d_out, int out_size, void* d_ws, size_t ws_size,
                              hipStream_t stream) {
    const float* hist = (const float*)d_in[0];
    // d_in[1] = mask [B,N] — all ones in this problem; ignored.
    char* ws = (char*)d_ws;
    const size_t xdBytes = (size_t)NB * NN * KD * sizeof(_Float16);        // 16.78 MB
    const size_t lvBytes = (size_t)NB * NN * NCAND * sizeof(float);        // 10.49 MB
    _Float16* xd = (_Float16*)ws;
    float* listv = (float*)(ws + xdBytes);
    short* listi = (short*)(ws + xdBytes + lvBytes);                        // 5.24 MB
    float* out = (float*)d_out;

    stats_split<<<NB * NN, 64, 0, stream>>>(hist, xd);
    gemm_topk<<<NB * 32 * CSPLIT, 256, 0, stream>>>(xd, listv, listi);
    merge_kernel<<<NB * NN / 4, 256, 0, stream>>>(listv, listi, out);
}